// Round 13
// baseline (304.616 us; speedup 1.0000x reference)
//
#include <hip/hip_runtime.h>
#include <hip/hip_bf16.h>

#define BB 8
#define NFQ 64
#define NUQ 1024
#define HH 8
#define SS 2176

typedef __attribute__((ext_vector_type(8))) short short8;
typedef __attribute__((ext_vector_type(4))) float f32x4;
typedef __attribute__((ext_vector_type(2))) unsigned int uint2_t;
typedef unsigned short ubf;

__device__ __forceinline__ ubf f2bf(float x) {
    unsigned u = __float_as_uint(x);
    u = u + 0x7fffu + ((u >> 16) & 1u);
    return (ubf)(u >> 16);
}
__device__ __forceinline__ unsigned pkbf(float a, float b) {
    __hip_bfloat162 h = __float22bfloat162_rn(make_float2(a, b));
    union { __hip_bfloat162 hh; unsigned u; } c; c.hh = h;
    return c.u;
}
__device__ __forceinline__ float bf2f(short v) {
    return __uint_as_float(((unsigned)(ubf)v) << 16);
}

// ---------------- Kernel 0: weight transpose prep (verified) ----------------
__global__ __launch_bounds__(256) void prep_kernel(
    const float* __restrict__ Wf, const float* __restrict__ Wu, const float* __restrict__ Wout,
    ubf* __restrict__ WfT, ubf* __restrict__ WuT, ubf* __restrict__ WoutT)
{
    __shared__ ubf tl[128 * 72];
    const int idx = blockIdx.x, tid = threadIdx.x;
    const float* src; ubf* dst; int F, dstride;
    if (idx < 48)       { F = 64; src = Wf + (size_t)idx * 64 * 128;        dst = WfT + (size_t)idx * 128 * 64;        dstride = 64; }
    else if (idx < 96)  { F = 32; src = Wu + (size_t)(idx - 48) * 32 * 128; dst = WuT + (size_t)(idx - 48) * 128 * 32; dstride = 32; }
    else                { F = 64; int s = idx - 96; src = Wout + (size_t)s * 64 * 128; dst = WoutT + s * 64; dstride = 1024; }
    const int pitch = F + 8;
    for (int i = tid; i < F * 32; i += 256) {
        int f = i >> 5, d0 = (i & 31) * 4;
        f32x4 v = *(const f32x4*)&src[f * 128 + d0];
        tl[(d0 + 0) * pitch + f] = f2bf(v[0]);
        tl[(d0 + 1) * pitch + f] = f2bf(v[1]);
        tl[(d0 + 2) * pitch + f] = f2bf(v[2]);
        tl[(d0 + 3) * pitch + f] = f2bf(v[3]);
    }
    __syncthreads();
    if (F == 64) {
        int d = tid >> 1, half = tid & 1;
#pragma unroll
        for (int jj = 0; jj < 4; ++jj)
            *(short8*)&dst[(size_t)d * dstride + half * 32 + jj * 8] =
                *(const short8*)&tl[d * pitch + half * 32 + jj * 8];
    } else {
        int d = tid & 127, fh = tid >> 7;
#pragma unroll
        for (int jj = 0; jj < 2; ++jj)
            *(short8*)&dst[(size_t)d * dstride + fh * 16 + jj * 8] =
                *(const short8*)&tl[d * pitch + fh * 16 + jj * 8];
    }
}

// ---------------- Kernel 1: QKV projections via MFMA (verified r9) ----------------
__global__ __launch_bounds__(256) void proj_kernel(
    const float* __restrict__ f0, const float* __restrict__ u0,
    const float* __restrict__ f1, const float* __restrict__ u1,
    const ubf* __restrict__ WfT, const ubf* __restrict__ WuT,
    const float* __restrict__ bfv, const float* __restrict__ buv,
    ubf* __restrict__ Qg, ubf* __restrict__ Kg, ubf* __restrict__ Vtg)
{
    __shared__ ubf xlds[32 * 64];
    __shared__ ubf outq[32 * 136];
    __shared__ ubf outk[32 * 136];
    __shared__ ubf outv[128 * 40];

    const int tid = threadIdx.x;
    const int bh = blockIdx.x / 17, j = blockIdx.x % 17;
    const int b = bh >> 3, h = bh & 7;
    const int w = tid >> 6, l = tid & 63, lg = l >> 4, dl = l & 15;
    const int dg0 = w * 2;

    const bool isF = (j == 0);
    const f32x4 zf = {0.f, 0.f, 0.f, 0.f};

    short8 af[3][2][2];
    f32x4 bv[3][2];

    const int up = isF ? 0 : ((j - 1) >> 3);
    const int ugrp = isF ? 0 : ((j - 1) & 7);
    const float* xpb = 0;
    if (!isF) xpb = (up ? u1 : u0) + (size_t)b * NUQ * 32;

    for (int c4 = 0; c4 < 4; ++c4) {
        int p, n0, s0;
        const float* xp;
        if (isF) {
            p = c4 >> 1; n0 = (c4 & 1) * 32;
            s0 = p ? 1088 + (c4 & 1) * 32 : (c4 & 1) * 32;
            xp = (p ? f1 : f0) + (size_t)b * NFQ * 64;
        } else {
            p = up; int c = ugrp * 4 + c4; n0 = 32 * c;
            s0 = (p ? 1152 : 64) + 32 * c;
            xp = xpb;
        }

        if (c4 == 0 || (isF && c4 == 2)) {
            if (isF) {
                const ubf* wt = WfT + (size_t)((h * 2 + p) * 3) * 8192;
#pragma unroll
                for (int k = 0; k < 3; ++k)
#pragma unroll
                    for (int g = 0; g < 2; ++g) {
                        af[k][g][0] = *(const short8*)&wt[(size_t)k * 8192 + ((dg0 + g) * 16 + dl) * 64 + lg * 8];
                        af[k][g][1] = *(const short8*)&wt[(size_t)k * 8192 + ((dg0 + g) * 16 + dl) * 64 + 32 + lg * 8];
                        bv[k][g] = *(const f32x4*)&bfv[((h * 2 + p) * 3 + k) * 128 + (dg0 + g) * 16 + 4 * lg];
                    }
            } else {
                const ubf* wt = WuT + (size_t)((h * 2 + p) * 3) * 4096;
#pragma unroll
                for (int k = 0; k < 3; ++k)
#pragma unroll
                    for (int g = 0; g < 2; ++g) {
                        af[k][g][0] = *(const short8*)&wt[(size_t)k * 4096 + ((dg0 + g) * 16 + dl) * 32 + lg * 8];
                        bv[k][g] = *(const f32x4*)&buv[((h * 2 + p) * 3 + k) * 128 + (dg0 + g) * 16 + 4 * lg];
                    }
            }
        }

        if (isF) {
            int row = tid >> 3, g = tid & 7;
            const float* s = &xp[(size_t)(n0 + row) * 64 + g * 8];
            f32x4 v0 = *(const f32x4*)&s[0];
            f32x4 v1 = *(const f32x4*)&s[4];
            union { unsigned u[4]; short8 s8; } pk;
            pk.u[0] = pkbf(v0[0], v0[1]); pk.u[1] = pkbf(v0[2], v0[3]);
            pk.u[2] = pkbf(v1[0], v1[1]); pk.u[3] = pkbf(v1[2], v1[3]);
            *(short8*)&xlds[row * 64 + ((g ^ (row & 7)) * 8)] = pk.s8;
        } else if (tid < 128) {
            int row = tid >> 2, g = tid & 3;
            const float* s = &xp[(size_t)(n0 + row) * 32 + g * 8];
            f32x4 v0 = *(const f32x4*)&s[0];
            f32x4 v1 = *(const f32x4*)&s[4];
            union { unsigned u[4]; short8 s8; } pk;
            pk.u[0] = pkbf(v0[0], v0[1]); pk.u[1] = pkbf(v0[2], v0[3]);
            pk.u[2] = pkbf(v1[0], v1[1]); pk.u[3] = pkbf(v1[2], v1[3]);
            *(short8*)&xlds[row * 64 + ((g ^ (row & 7)) * 8)] = pk.s8;
        }
        __syncthreads();

        short8 bx0[2], bx1[2];
#pragma unroll
        for (int tile = 0; tile < 2; ++tile) {
            const int row = tile * 16 + dl;
            bx0[tile] = *(const short8*)&xlds[row * 64 + ((lg ^ (row & 7)) * 8)];
            if (isF)
                bx1[tile] = *(const short8*)&xlds[row * 64 + (((4 + lg) ^ (row & 7)) * 8)];
        }

#pragma unroll
        for (int k = 0; k < 3; ++k)
#pragma unroll
            for (int g = 0; g < 2; ++g)
#pragma unroll
                for (int tile = 0; tile < 2; ++tile) {
                    f32x4 acc = __builtin_amdgcn_mfma_f32_16x16x32_bf16(af[k][g][0], bx0[tile], zf, 0, 0, 0);
                    if (isF)
                        acc = __builtin_amdgcn_mfma_f32_16x16x32_bf16(af[k][g][1], bx1[tile], acc, 0, 0, 0);
                    if (k < 2) {
                        ubf* o = k ? outk : outq;
                        uint2_t wv;
                        wv.x = pkbf(acc[0] + bv[k][g][0], acc[1] + bv[k][g][1]);
                        wv.y = pkbf(acc[2] + bv[k][g][2], acc[3] + bv[k][g][3]);
                        *(uint2_t*)&o[(tile * 16 + dl) * 136 + (dg0 + g) * 16 + 4 * lg] = wv;
                    } else {
                        int pos = (dl & 3) + 8 * ((dl >> 2) & 3) + 4 * tile;
#pragma unroll
                        for (int r = 0; r < 4; ++r)
                            outv[((dg0 + g) * 16 + 4 * lg + r) * 40 + pos] = f2bf(acc[r] + bv[2][g][r]);
                    }
                }
        __syncthreads();

        {
            int row = tid >> 3, c16 = (tid & 7) * 16;
            size_t qbase = ((size_t)bh * SS + s0 + row) * 128 + c16;
            *(short8*)&Qg[qbase]     = *(const short8*)&outq[row * 136 + c16];
            *(short8*)&Qg[qbase + 8] = *(const short8*)&outq[row * 136 + c16 + 8];
            *(short8*)&Kg[qbase]     = *(const short8*)&outk[row * 136 + c16];
            *(short8*)&Kg[qbase + 8] = *(const short8*)&outk[row * 136 + c16 + 8];
            int dd = tid >> 1, half = tid & 1;
            size_t vbase = ((size_t)bh * 128 + dd) * SS + s0 + half * 16;
            *(short8*)&Vtg[vbase]     = *(const short8*)&outv[dd * 40 + half * 16];
            *(short8*)&Vtg[vbase + 8] = *(const short8*)&outv[dd * 40 + half * 16 + 8];
        }
    }
}

// ---------------- Kernel 2: flash attention — 4 waves x 48 q; 64-key dbuf tiles ----------------
__global__ __launch_bounds__(256) void attn_kernel(
    const ubf* __restrict__ Qg, const ubf* __restrict__ Kg, const ubf* __restrict__ Vtg,
    ubf* __restrict__ attnout)
{
    __shared__ ubf Klds[2][64 * 128];   // 16KB each; group-swizzled: phys_g = g ^ (row&7)
    __shared__ ubf Vlds[2][128 * 64];   // 16KB each; group-swizzled: phys_g = g ^ (row&7)

    const int tid = threadIdx.x;
    const int swz = (blockIdx.x & 7) * 96 + (blockIdx.x >> 3);  // 768 = 8 XCD x 96, bijective
    const int bh = swz / 12;
    const int qc = swz % 12;
    const int b = bh >> 3, h = bh & 7;
    const int w = tid >> 6, l = tid & 63, lg = l >> 4, dl = l & 15;
    const int qbase = qc * 192 + w * 48;

    const ubf* Qbh = Qg + (size_t)bh * SS * 128;
    const ubf* Kbh = Kg + (size_t)bh * SS * 128;
    const ubf* Vbh = Vtg + (size_t)bh * 128 * SS;

    // per-set query rows; tail sets clamp (loads safe, stores predicated)
    int qs[3]; bool qv[3];
#pragma unroll
    for (int s = 0; s < 3; ++s) {
        int q0 = qbase + s * 16;
        qv[s] = q0 < SS;
        qs[s] = (qv[s] ? q0 : SS - 16) + dl;
    }

    short8 qf[3][4];
#pragma unroll
    for (int s = 0; s < 3; ++s)
#pragma unroll
        for (int dc = 0; dc < 4; ++dc)
            qf[s][dc] = *(const short8*)&Qbh[(size_t)qs[s] * 128 + dc * 32 + lg * 8];

    f32x4 ot[3][8];
    const f32x4 zf = {0.f, 0.f, 0.f, 0.f};
#pragma unroll
    for (int s = 0; s < 3; ++s)
#pragma unroll
        for (int i = 0; i < 8; ++i) ot[s][i] = zf;
    float lsum[3] = {0.f, 0.f, 0.f};

    const float sc = 0.08838834764831845f * 1.44269504088896340736f;

    // staging geometry: 16 slots x 512 elems each for K and V (4 slots per wave)
    const int lh = l >> 4;              // 0..3
    const int ldsw = w * 2048 + l * 8;  // LDS elem offset of slot j=0 for this thread
    const int kr0 = w * 16 + lh;        // K row for j=0 (j adds 4)
    const int vd0 = w * 32 + (l >> 3);  // V d-row for j=0 (j adds 8)
    const int vgc = ((l & 7) ^ ((l >> 3) & 7)) * 8;   // V src col group (j-invariant)

    short8 ks[4], vs[4];
#pragma unroll
    for (int j = 0; j < 4; ++j) {
        int r = kr0 + j * 4;
        int g = ((l & 15) ^ (r & 7)) * 8;
        ks[j] = *(const short8*)&Kbh[(size_t)r * 128 + g];
        vs[j] = *(const short8*)&Vbh[(size_t)(vd0 + j * 8) * SS + vgc];
    }
#pragma unroll
    for (int j = 0; j < 4; ++j) {
        *(short8*)&Klds[0][ldsw + j * 512] = ks[j];
        *(short8*)&Vlds[0][ldsw + j * 512] = vs[j];
    }
    __syncthreads();

    int cur = 0;
    for (int it = 0; it < 34; ++it) {
        if (it < 33) {  // prefetch next 64-key tile into registers
            const size_t kb = (size_t)(it + 1) * 64;
#pragma unroll
            for (int j = 0; j < 4; ++j) {
                int r = kr0 + j * 4;
                int g = ((l & 15) ^ (r & 7)) * 8;
                ks[j] = *(const short8*)&Kbh[(kb + r) * 128 + g];
                vs[j] = *(const short8*)&Vbh[(size_t)(vd0 + j * 8) * SS + kb + vgc];
            }
        }
        const ubf* Kc = Klds[cur];
        const ubf* Vc = Vlds[cur];

#pragma unroll
        for (int kh = 0; kh < 2; ++kh) {
            f32x4 s0[3], s1[3];
#pragma unroll
            for (int s = 0; s < 3; ++s) { s0[s] = zf; s1[s] = zf; }

            __builtin_amdgcn_s_setprio(1);
#pragma unroll
            for (int dc = 0; dc < 4; ++dc) {
                const int col = ((dc * 4 + lg) ^ (dl & 7)) * 8;
                short8 k0 = *(const short8*)&Kc[(kh * 32 + dl) * 128 + col];
                short8 k1 = *(const short8*)&Kc[(kh * 32 + 16 + dl) * 128 + col];
#pragma unroll
                for (int s = 0; s < 3; ++s) {
                    s0[s] = __builtin_amdgcn_mfma_f32_16x16x32_bf16(k0, qf[s][dc], s0[s], 0, 0, 0);
                    s1[s] = __builtin_amdgcn_mfma_f32_16x16x32_bf16(k1, qf[s][dc], s1[s], 0, 0, 0);
                }
            }
            __builtin_amdgcn_s_setprio(0);

            // fixed-max softmax (exact: m cancels in P/sum)
            union { unsigned u[4]; short8 s8; } P[3];
#pragma unroll
            for (int s = 0; s < 3; ++s) {
                float e0 = __builtin_amdgcn_exp2f(s0[s][0] * sc);
                float e1 = __builtin_amdgcn_exp2f(s0[s][1] * sc);
                float e2 = __builtin_amdgcn_exp2f(s0[s][2] * sc);
                float e3 = __builtin_amdgcn_exp2f(s0[s][3] * sc);
                float e4 = __builtin_amdgcn_exp2f(s1[s][0] * sc);
                float e5 = __builtin_amdgcn_exp2f(s1[s][1] * sc);
                float e6 = __builtin_amdgcn_exp2f(s1[s][2] * sc);
                float e7 = __builtin_amdgcn_exp2f(s1[s][3] * sc);
                lsum[s] += ((e0 + e1) + (e2 + e3)) + ((e4 + e5) + (e6 + e7));
                P[s].u[0] = pkbf(e0, e1); P[s].u[1] = pkbf(e2, e3);
                P[s].u[2] = pkbf(e4, e5); P[s].u[3] = pkbf(e6, e7);
            }

            __builtin_amdgcn_s_setprio(1);
#pragma unroll
            for (int dt = 0; dt < 8; ++dt) {
                short8 vf = *(const short8*)&Vc[(dt * 16 + dl) * 64 + (((kh * 4 + lg) ^ (dl & 7)) * 8)];
#pragma unroll
                for (int s = 0; s < 3; ++s)
                    ot[s][dt] = __builtin_amdgcn_mfma_f32_16x16x32_bf16(vf, P[s].s8, ot[s][dt], 0, 0, 0);
            }
            __builtin_amdgcn_s_setprio(0);
        }

        if (it < 33) {
#pragma unroll
            for (int j = 0; j < 4; ++j) {
                *(short8*)&Klds[cur ^ 1][ldsw + j * 512] = ks[j];
                *(short8*)&Vlds[cur ^ 1][ldsw + j * 512] = vs[j];
            }
            cur ^= 1;
            __syncthreads();
        }
    }

#pragma unroll
    for (int s = 0; s < 3; ++s) {
        float ls = lsum[s];
        ls += __shfl_xor(ls, 16);
        ls += __shfl_xor(ls, 32);
        const float inv = 1.f / ls;
        if (qv[s]) {
            ubf* dst = attnout + ((size_t)b * SS + qs[s]) * 1024 + h * 128;
#pragma unroll
            for (int dt = 0; dt < 8; ++dt) {
                f32x4 o = ot[s][dt] * inv;
                uint2_t wv;
                wv.x = pkbf(o[0], o[1]); wv.y = pkbf(o[2], o[3]);
                *(uint2_t*)&dst[dt * 16 + 4 * lg] = wv;
            }
        }
    }
}

// ---------------- Kernel 3: output projection via MFMA (verified r9) ----------------
__global__ __launch_bounds__(256) void outproj_kernel(
    const ubf* __restrict__ attnout, const ubf* __restrict__ WoutT,
    const float* __restrict__ bout, float* __restrict__ out)
{
    __shared__ ubf alds[32 * 1024];
    const int tid = threadIdx.x;
    const int row0 = blockIdx.x * 32;
    const int w = tid >> 6, l = tid & 63, lg = l >> 4, dl = l & 15;
    const int dg0 = w * 2;
    const f32x4 zf = {0.f, 0.f, 0.f, 0.f};

#pragma unroll
    for (int pz = 0; pz < 2; ++pz) {
        int row = pz * 16 + (tid >> 4);
        int cl = tid & 15;
#pragma unroll
        for (int jj = 0; jj < 8; ++jj) {
            int g = cl + 16 * jj;
            short8 v = *(const short8*)&attnout[(size_t)(row0 + row) * 1024 + g * 8];
            *(short8*)&alds[row * 1024 + ((g ^ (row & 7)) * 8)] = v;
        }
    }
    __syncthreads();

    f32x4 acc[2][2];
    acc[0][0] = zf; acc[0][1] = zf; acc[1][0] = zf; acc[1][1] = zf;

    for (int dc = 0; dc < 32; ++dc) {
        short8 a0 = *(const short8*)&WoutT[(size_t)((dg0 + 0) * 16 + dl) * 1024 + dc * 32 + lg * 8];
        short8 a1 = *(const short8*)&WoutT[(size_t)((dg0 + 1) * 16 + dl) * 1024 + dc * 32 + lg * 8];
        short8 b0 = *(const short8*)&alds[dl * 1024 + (((dc * 4 + lg) ^ (dl & 7)) * 8)];
        short8 b1 = *(const short8*)&alds[(16 + dl) * 1024 + (((dc * 4 + lg) ^ (dl & 7)) * 8)];
        acc[0][0] = __builtin_amdgcn_mfma_f32_16x16x32_bf16(a0, b0, acc[0][0], 0, 0, 0);
        acc[0][1] = __builtin_amdgcn_mfma_f32_16x16x32_bf16(a0, b1, acc[0][1], 0, 0, 0);
        acc[1][0] = __builtin_amdgcn_mfma_f32_16x16x32_bf16(a1, b0, acc[1][0], 0, 0, 0);
        acc[1][1] = __builtin_amdgcn_mfma_f32_16x16x32_bf16(a1, b1, acc[1][1], 0, 0, 0);
    }

#pragma unroll
    for (int g = 0; g < 2; ++g) {
        f32x4 bb = *(const f32x4*)&bout[(dg0 + g) * 16 + 4 * lg];
#pragma unroll
        for (int tile = 0; tile < 2; ++tile) {
            f32x4 o = acc[g][tile] + bb;
            *(f32x4*)&out[((size_t)row0 + tile * 16 + dl) * 128 + (dg0 + g) * 16 + 4 * lg] = o;
        }
    }
}

extern "C" void kernel_launch(void* const* d_in, const int* in_sizes, int n_in,
                              void* d_out, int out_size, void* d_ws, size_t ws_size,
                              hipStream_t stream) {
    const float* f0  = (const float*)d_in[0];
    const float* u0  = (const float*)d_in[1];
    const float* f1  = (const float*)d_in[2];
    const float* u1  = (const float*)d_in[3];
    const float* Wf  = (const float*)d_in[4];
    const float* bfv = (const float*)d_in[5];
    const float* Wu  = (const float*)d_in[6];
    const float* buv = (const float*)d_in[7];
    const float* Wout = (const float*)d_in[8];
    const float* bout = (const float*)d_in[9];
    float* out = (float*)d_out;

    char* ws = (char*)d_ws;
    const size_t qkv_bytes = (size_t)BB * HH * SS * 128 * sizeof(ubf); // 35,651,584
    ubf* Qg  = (ubf*)ws;
    ubf* Kg  = (ubf*)(ws + qkv_bytes);
    ubf* Vtg = (ubf*)(ws + 2 * qkv_bytes);
    ubf* attnout = (ubf*)(ws + 3 * qkv_bytes);
    ubf* WfT   = (ubf*)(ws + 4 * qkv_bytes);
    ubf* WuT   = (ubf*)(ws + 4 * qkv_bytes + 786432);
    ubf* WoutT = (ubf*)(ws + 4 * qkv_bytes + 786432 + 393216);

    prep_kernel<<<dim3(112), dim3(256), 0, stream>>>(Wf, Wu, Wout, WfT, WuT, WoutT);
    proj_kernel<<<dim3(64 * 17), dim3(256), 0, stream>>>(f0, u0, f1, u1, WfT, WuT, bfv, buv, Qg, Kg, Vtg);
    attn_kernel<<<dim3(768), dim3(256), 0, stream>>>(Qg, Kg, Vtg, attnout);
    outproj_kernel<<<dim3(544), dim3(256), 0, stream>>>(attnout, WoutT, bout, out);
}